// Round 22
// baseline (184.847 us; speedup 1.0000x reference)
//
#include <hip/hip_runtime.h>
#include <hip/hip_bf16.h>

typedef __attribute__((ext_vector_type(8))) short bf16x8;
typedef __attribute__((ext_vector_type(4))) float f32x4;
typedef __attribute__((ext_vector_type(4))) unsigned int u32x4;
typedef unsigned long long ull;

#define RT 128              // rows per block = 4 waves x 32
#define NB (262144 / RT)    // 2048
#define NFRAG 19            // 0-3 w1f, 4-11 w2f, 12-13 w3f, 14-17 b2f, 18 b3f

// Per-wave private LDS region (NO cross-wave sharing -> zero barriers).
#define WREG 12032
#define SMEM_BYTES (4 * WREG)   // 48,128 B -> 3 blocks/CU
#define XW_OFF 0            // x: [4][32][40] bf16 = 10240 B (row stride 80B; aug@k24)
#define YW_OFF 10240        // y: [2][32][12] bf16 =  1536 B
#define EW_OFF 11776        // e: [32] f32         =   128 B

// RNE 3-VALU pack (r6-verified) — weights / state.
__device__ __forceinline__ unsigned pk2(float lo, float hi) {
  union { float f; unsigned u; } a, b;
  a.f = lo; b.f = hi;
  return __builtin_amdgcn_perm(b.u + 0x8000u, a.u + 0x8000u, 0x07060302u);
}
// truncating 1-VALU pack for inter-layer activations (r17-verified)
__device__ __forceinline__ unsigned pk2t(float lo, float hi) {
  union { float f; unsigned u; } a, b;
  a.f = lo; b.f = hi;
  return __builtin_amdgcn_perm(b.u, a.u, 0x07060302u);
}
__device__ __forceinline__ void unp4(ull v, float* d) {
  unsigned a = (unsigned)v, b = (unsigned)(v >> 32);
  union { unsigned u; float f; } x;
  x.u = a << 16;         d[0] = x.f;
  x.u = a & 0xffff0000u; d[1] = x.f;
  x.u = b << 16;         d[2] = x.f;
  x.u = b & 0xffff0000u; d[3] = x.f;
}
__device__ __forceinline__ bf16x8 mkfrag(unsigned w0, unsigned w1, unsigned w2, unsigned w3) {
  union { bf16x8 v; unsigned u[4]; } U;
  U.u[0] = w0; U.u[1] = w1; U.u[2] = w2; U.u[3] = w3;
  return U.v;
}
__device__ __forceinline__ f32x4 mfma16(bf16x8 a, bf16x8 b, f32x4 c) {
  return __builtin_amdgcn_mfma_f32_16x16x32_bf16(a, b, c, 0, 0, 0);
}

// ================= prep kernel: pack weight fragments once (r18-verified) =================
__global__ void wpack(const float* __restrict__ W1, const float* __restrict__ b1,
                      const float* __restrict__ W2, const float* __restrict__ b2,
                      const float* __restrict__ W3, const float* __restrict__ b3,
                      u32x4* __restrict__ ws)
{
  const int pc = blockIdx.x;       // 0..23
  const int lane = threadIdx.x;    // 0..63
  const int q = lane & 15, g = lane >> 4;
  int mpsi[4];
  #pragma unroll
  for (int mt = 0; mt < 4; ++mt)
    mpsi[mt] = 32*(mt>>1) + 8*(q>>2) + 4*(mt&1) + (q&3);

  const float* W1g = W1 + pc * 24 * 64;
  const float* b1g = b1 + pc * 64;
  const float* W2g = W2 + pc * 64 * 64;
  const float* b2g = b2 + pc * 64;
  const float* W3g = W3 + pc * 64 * 12;
  const float* b3g = b3 + pc * 12;
  u32x4* dst = ws + pc * NFRAG * 64 + lane;

  #pragma unroll
  for (int mt = 0; mt < 4; ++mt) {
    unsigned u[4];
    #pragma unroll
    for (int wq = 0; wq < 4; ++wq) {
      int k0 = 8*g + 2*wq;
      float v0 = (k0 < 24) ? W1g[k0*64 + mpsi[mt]] : ((k0 == 24) ? b1g[mpsi[mt]] : 0.f);
      float v1 = (k0+1 < 24) ? W1g[(k0+1)*64 + mpsi[mt]] : 0.f;
      u[wq] = pk2(v0, v1);
    }
    u32x4 t; t[0]=u[0]; t[1]=u[1]; t[2]=u[2]; t[3]=u[3];
    dst[mt * 64] = t;
  }
  #pragma unroll
  for (int kt = 0; kt < 2; ++kt)
    #pragma unroll
    for (int mt = 0; mt < 4; ++mt) {
      unsigned u[4];
      #pragma unroll
      for (int wq = 0; wq < 4; ++wq) {
        int k0 = 32*kt + 8*g + 2*wq;
        u[wq] = pk2(W2g[k0*64 + mpsi[mt]], W2g[(k0+1)*64 + mpsi[mt]]);
      }
      u32x4 t; t[0]=u[0]; t[1]=u[1]; t[2]=u[2]; t[3]=u[3];
      dst[(4 + kt*4 + mt) * 64] = t;
    }
  #pragma unroll
  for (int kt = 0; kt < 2; ++kt) {
    unsigned u[4];
    #pragma unroll
    for (int wq = 0; wq < 4; ++wq) {
      int k0 = 32*kt + 8*g + 2*wq;
      float v0 = (q < 12) ? W3g[k0*12 + q]     : 0.f;
      float v1 = (q < 12) ? W3g[(k0+1)*12 + q] : 0.f;
      u[wq] = pk2(v0, v1);
    }
    u32x4 t; t[0]=u[0]; t[1]=u[1]; t[2]=u[2]; t[3]=u[3];
    dst[(12 + kt) * 64] = t;
  }
  #pragma unroll
  for (int mt = 0; mt < 4; ++mt) {
    f32x4 bv;
    #pragma unroll
    for (int r = 0; r < 4; ++r) bv[r] = b2g[32*(mt>>1) + 8*g + 4*(mt&1) + r];
    union { f32x4 f; u32x4 u; } U; U.f = bv;
    dst[(14 + mt) * 64] = U.u;
  }
  {
    f32x4 bv;
    #pragma unroll
    for (int r = 0; r < 4; ++r) {
      int m = 4*g + r;
      bv[r] = (m < 12) ? b3g[m] : 0.f;
    }
    union { f32x4 f; u32x4 u; } U; U.f = bv;
    dst[18 * 64] = U.u;
  }
}

// ================= ROUND-22 main: zero-barrier, FIXED prologue =================
// r21's absmax 9.47 was a prologue LDS race: the staging slab overlay of the x
// region was clobbered by ch=0's x-writes before ch=1's reads. Fix: NO staging
// — each lane (q, g<3) loads its f32x4 directly from global (16B-aligned,
// each 16B segment read exactly once per wave). Everything else = r21:
// no __syncthreads anywhere; wave owns 32 rows x 8 (p,c) x 3 stages;
// register-local port-sum; wave-private LDS x repack.
// psi-16x16 (r8), pk2t hops (r17), prepack (r18).
__global__ __launch_bounds__(256, 3) void rrsep(
    const float* __restrict__ y_real, const float* __restrict__ y_imag,
    const u32x4* __restrict__ wsf, float* __restrict__ out)
{
  __shared__ __align__(16) char smem[SMEM_BYTES];
  const int tid  = (int)threadIdx.x;
  const int lane = tid & 63;
  const int w    = tid >> 6;
  const int q    = lane & 15;
  const int g    = lane >> 4;
  char* wbase = smem + w * WREG;
  unsigned short* xw = (unsigned short*)(wbase + XW_OFF);
  char*           yw = wbase + YW_OFF;
  float*          ew = (float*)(wbase + EW_OFF);
  const long wr0 = (long)blockIdx.x * RT + w * 32;

  // ---------------- prologue: DIRECT global loads (no staging, no race) ----------------
  {
    #pragma unroll
    for (int ch = 0; ch < 2; ++ch) {
      const int row = 16 * ch + q;
      f32x4 v0 = {0.f,0.f,0.f,0.f}, v1 = {0.f,0.f,0.f,0.f};
      if (g < 3) {
        v0 = *(const f32x4*)(y_real + (wr0 + row) * 12 + 4 * g);
        v1 = *(const f32x4*)(y_imag + (wr0 + row) * 12 + 4 * g);
      }
      float acc = v0[0]*v0[0]+v0[1]*v0[1]+v0[2]*v0[2]+v0[3]*v0[3]
                + v1[0]*v1[0]+v1[1]*v1[1]+v1[2]*v1[2]+v1[3]*v1[3];
      acc += __shfl_xor(acc, 16);
      acc += __shfl_xor(acc, 32);
      const float e   = sqrtf(acc * (1.f / 12.f));
      const float inv = 1.f / (e + 1e-8f);
      if (g == 0) ew[row] = e;
      if (g < 3) {
        unsigned a0 = pk2(v0[0]*inv, v0[1]*inv), a1 = pk2(v0[2]*inv, v0[3]*inv);
        unsigned b0 = pk2(v1[0]*inv, v1[1]*inv), b1 = pk2(v1[2]*inv, v1[3]*inv);
        *(ull*)(yw + row * 24 + 8 * g)       = (ull)a0 | ((ull)a1 << 32);
        *(ull*)(yw + 768 + row * 24 + 8 * g) = (ull)b0 | ((ull)b1 << 32);
        #pragma unroll
        for (int p = 0; p < 4; ++p) {
          char* xrp = (char*)xw + p * 2560 + row * 80;
          *(ull*)(xrp + 8 * g)      = (ull)a0 | ((ull)a1 << 32);
          *(ull*)(xrp + 24 + 8 * g) = (ull)b0 | ((ull)b1 << 32);
        }
      } else {   // g==3: aug slot k24..31 = {1, 0...}, written once, never touched again
        u32x4 t; t[0] = pk2(1.f, 0.f); t[1] = 0u; t[2] = 0u; t[3] = 0u;
        #pragma unroll
        for (int p = 0; p < 4; ++p)
          *(u32x4*)((char*)xw + p * 2560 + row * 80 + 48) = t;
      }
    }
  }

  // ---------------- stage loop: NO barriers anywhere ----------------
  #pragma unroll 1
  for (int s = 0; s < 3; ++s) {
    unsigned stash[4][2][2];   // s<2: packed c0 x-halves (written c==0, flushed c==1)
    f32x4 vc0[4][2];           // s==2: c0 final values

    #pragma unroll
    for (int c = 0; c < 2; ++c) {
      f32x4 o[4][2];           // [p][ch] — static indexing via full unroll (rule #20)

      #pragma unroll
      for (int p = 0; p < 4; ++p) {
        const u32x4* wb = wsf + ((s * 4 + p) * 2 + c) * NFRAG * 64 + lane;
        bf16x8 w1f[4], w2f[2][4], w3f[2];
        f32x4 b2f[4], b3f;
        #pragma unroll
        for (int mt = 0; mt < 4; ++mt) {
          union { u32x4 u; bf16x8 v; } U; U.u = wb[mt * 64];
          w1f[mt] = U.v;
        }
        #pragma unroll
        for (int kt = 0; kt < 2; ++kt)
          #pragma unroll
          for (int mt = 0; mt < 4; ++mt) {
            union { u32x4 u; bf16x8 v; } U; U.u = wb[(4 + kt*4 + mt) * 64];
            w2f[kt][mt] = U.v;
          }
        #pragma unroll
        for (int kt = 0; kt < 2; ++kt) {
          union { u32x4 u; bf16x8 v; } U; U.u = wb[(12 + kt) * 64];
          w3f[kt] = U.v;
        }
        #pragma unroll
        for (int mt = 0; mt < 4; ++mt) {
          union { u32x4 u; f32x4 f; } U; U.u = wb[(14 + mt) * 64];
          b2f[mt] = U.f;
        }
        {
          union { u32x4 u; f32x4 f; } U; U.u = wb[18 * 64];
          b3f = U.f;
        }

        #pragma unroll
        for (int ch = 0; ch < 2; ++ch) {
          const int row = 16 * ch + q;
          bf16x8 xb = *(const bf16x8*)((char*)xw + p * 2560 + row * 80 + 16 * g);

          f32x4 c1[4];
          #pragma unroll
          for (int mt = 0; mt < 4; ++mt) c1[mt] = mfma16(w1f[mt], xb, f32x4{0.f,0.f,0.f,0.f});

          bf16x8 fr1[2];
          #pragma unroll
          for (int kt = 0; kt < 2; ++kt)
            fr1[kt] = mkfrag(
              pk2t(fmaxf(c1[2*kt][0], 0.f),   fmaxf(c1[2*kt][1], 0.f)),
              pk2t(fmaxf(c1[2*kt][2], 0.f),   fmaxf(c1[2*kt][3], 0.f)),
              pk2t(fmaxf(c1[2*kt+1][0], 0.f), fmaxf(c1[2*kt+1][1], 0.f)),
              pk2t(fmaxf(c1[2*kt+1][2], 0.f), fmaxf(c1[2*kt+1][3], 0.f)));

          f32x4 c2[4];
          #pragma unroll
          for (int mt = 0; mt < 4; ++mt) {
            c2[mt] = mfma16(w2f[0][mt], fr1[0], b2f[mt]);
            c2[mt] = mfma16(w2f[1][mt], fr1[1], c2[mt]);
          }
          bf16x8 fr2[2];
          #pragma unroll
          for (int kt = 0; kt < 2; ++kt)
            fr2[kt] = mkfrag(
              pk2t(fmaxf(c2[2*kt][0], 0.f),   fmaxf(c2[2*kt][1], 0.f)),
              pk2t(fmaxf(c2[2*kt][2], 0.f),   fmaxf(c2[2*kt][3], 0.f)),
              pk2t(fmaxf(c2[2*kt+1][0], 0.f), fmaxf(c2[2*kt+1][1], 0.f)),
              pk2t(fmaxf(c2[2*kt+1][2], 0.f), fmaxf(c2[2*kt+1][3], 0.f)));

          f32x4 c3 = mfma16(w3f[0], fr2[0], b3f);
          c3 = mfma16(w3f[1], fr2[1], c3);
          o[p][ch] = c3;
        }
      }

      // ---- in-register combine for channel c (wave-private) ----
      #pragma unroll
      for (int ch = 0; ch < 2; ++ch) {
        const int row = 16 * ch + q;
        f32x4 sum;
        #pragma unroll
        for (int j = 0; j < 4; ++j)
          sum[j] = o[0][ch][j] + o[1][ch][j] + o[2][ch][j] + o[3][ch][j];
        if (g < 3) {
          float yn[4];
          unp4(*(const ull*)(yw + c * 768 + row * 24 + 8 * g), yn);
          f32x4 rr;
          #pragma unroll
          for (int j = 0; j < 4; ++j) rr[j] = yn[j] - sum[j];

          if (s < 2) {
            if (c == 0) {
              #pragma unroll
              for (int p = 0; p < 4; ++p) {
                f32x4 nx;
                #pragma unroll
                for (int j = 0; j < 4; ++j) nx[j] = o[p][ch][j] + rr[j];
                stash[p][ch][0] = pk2(nx[0], nx[1]);
                stash[p][ch][1] = pk2(nx[2], nx[3]);
              }
            } else {
              #pragma unroll
              for (int p = 0; p < 4; ++p) {
                f32x4 nx;
                #pragma unroll
                for (int j = 0; j < 4; ++j) nx[j] = o[p][ch][j] + rr[j];
                char* xrp = (char*)xw + p * 2560 + row * 80;
                *(ull*)(xrp + 8 * g) = (ull)stash[p][ch][0] | ((ull)stash[p][ch][1] << 32);
                unsigned i0 = pk2(nx[0], nx[1]), i1 = pk2(nx[2], nx[3]);
                *(ull*)(xrp + 24 + 8 * g) = (ull)i0 | ((ull)i1 << 32);
              }
            }
          } else {
            const float e = ew[row];
            if (c == 0) {
              #pragma unroll
              for (int p = 0; p < 4; ++p) {
                #pragma unroll
                for (int j = 0; j < 4; ++j) vc0[p][ch][j] = (o[p][ch][j] + rr[j]) * e;
              }
            } else {
              float* ob = out + (wr0 + row) * 96 + 8 * g;
              #pragma unroll
              for (int p = 0; p < 4; ++p) {
                f32x4 A, B;
                A[0] = vc0[p][ch][0]; A[1] = (o[p][ch][0] + rr[0]) * e;
                A[2] = vc0[p][ch][1]; A[3] = (o[p][ch][1] + rr[1]) * e;
                B[0] = vc0[p][ch][2]; B[1] = (o[p][ch][2] + rr[2]) * e;
                B[2] = vc0[p][ch][3]; B[3] = (o[p][ch][3] + rr[3]) * e;
                *(f32x4*)(ob + p * 24)     = A;
                *(f32x4*)(ob + p * 24 + 4) = B;
              }
            }
          }
        }
      }
    }
  }
}

extern "C" void kernel_launch(void* const* d_in, const int* in_sizes, int n_in,
                              void* d_out, int out_size, void* d_ws, size_t ws_size,
                              hipStream_t stream) {
  const float* y_real = (const float*)d_in[0];
  const float* y_imag = (const float*)d_in[1];
  const float* W1 = (const float*)d_in[2];
  const float* b1 = (const float*)d_in[3];
  const float* W2 = (const float*)d_in[4];
  const float* b2 = (const float*)d_in[5];
  const float* W3 = (const float*)d_in[6];
  const float* b3 = (const float*)d_in[7];
  float* out = (float*)d_out;
  u32x4* ws = (u32x4*)d_ws;   // needs 24*19*64*16 = 466,944 B

  hipLaunchKernelGGL(wpack, dim3(24), dim3(64), 0, stream,
                     W1, b1, W2, b2, W3, b3, ws);
  hipLaunchKernelGGL(rrsep, dim3(NB), dim3(256), 0, stream,
                     y_real, y_imag, ws, out);
}

// Round 23
// 149.877 us; speedup vs baseline: 1.2333x; 1.2333x over previous
//
#include <hip/hip_runtime.h>
#include <hip/hip_bf16.h>

typedef __attribute__((ext_vector_type(8))) short bf16x8;
typedef __attribute__((ext_vector_type(4))) float f32x4;
typedef __attribute__((ext_vector_type(4))) unsigned int u32x4;
typedef unsigned long long ull;

#define RT 64
#define NB (262144 / RT)
#define XSTR 32
#define NFRAG 19   // 0-3 w1f, 4-11 w2f[kt*4+mt], 12-13 w3f, 14-17 b2f, 18 b3f

// LDS byte offsets — 47,744 B/block -> 3 blocks/CU (143.2KB <= 160KB)
#define X_OFF 0          // x: [4][64][32] bf16    = 16384 B
#define O_OFF 16384      // o: [4][2][65][12] f32  = 24960 B
#define Y_OFF 41344      // y: [2][64][12] f32     =  6144 B
#define E_OFF 47488      // e: [64] f32            =   256 B
#define SMEM_BYTES 47744

// RNE 3-VALU pack (r6-verified) — weights / state / prologue.
__device__ __forceinline__ unsigned pk2(float lo, float hi) {
  union { float f; unsigned u; } a, b;
  a.f = lo; b.f = hi;
  return __builtin_amdgcn_perm(b.u + 0x8000u, a.u + 0x8000u, 0x07060302u);
}
// truncating 1-VALU pack for inter-layer activations (r17-verified)
__device__ __forceinline__ unsigned pk2t(float lo, float hi) {
  union { float f; unsigned u; } a, b;
  a.f = lo; b.f = hi;
  return __builtin_amdgcn_perm(b.u, a.u, 0x07060302u);
}
__device__ __forceinline__ bf16x8 mkfrag(unsigned w0, unsigned w1, unsigned w2, unsigned w3) {
  union { bf16x8 v; unsigned u[4]; } U;
  U.u[0] = w0; U.u[1] = w1; U.u[2] = w2; U.u[3] = w3;
  return U.v;
}
__device__ __forceinline__ f32x4 mfma16(bf16x8 a, bf16x8 b, f32x4 c) {
  return __builtin_amdgcn_mfma_f32_16x16x32_bf16(a, b, c, 0, 0, 0);
}

// ================= prep kernel: pack weight fragments once (r18-verified) =================
__global__ void wpack(const float* __restrict__ W1, const float* __restrict__ b1,
                      const float* __restrict__ W2, const float* __restrict__ b2,
                      const float* __restrict__ W3, const float* __restrict__ b3,
                      u32x4* __restrict__ ws)
{
  const int pc = blockIdx.x;       // 0..23 = (s*4+p)*2+c
  const int lane = threadIdx.x;    // 0..63
  const int q = lane & 15, g = lane >> 4;
  int mpsi[4];
  #pragma unroll
  for (int mt = 0; mt < 4; ++mt)
    mpsi[mt] = 32*(mt>>1) + 8*(q>>2) + 4*(mt&1) + (q&3);

  const float* W1g = W1 + pc * 24 * 64;
  const float* b1g = b1 + pc * 64;
  const float* W2g = W2 + pc * 64 * 64;
  const float* b2g = b2 + pc * 64;
  const float* W3g = W3 + pc * 64 * 12;
  const float* b3g = b3 + pc * 12;
  u32x4* dst = ws + pc * NFRAG * 64 + lane;   // frag f at dst[f*64]

  #pragma unroll
  for (int mt = 0; mt < 4; ++mt) {
    unsigned u[4];
    #pragma unroll
    for (int wq = 0; wq < 4; ++wq) {
      int k0 = 8*g + 2*wq;
      float v0 = (k0 < 24) ? W1g[k0*64 + mpsi[mt]] : ((k0 == 24) ? b1g[mpsi[mt]] : 0.f);
      float v1 = (k0+1 < 24) ? W1g[(k0+1)*64 + mpsi[mt]] : 0.f;
      u[wq] = pk2(v0, v1);
    }
    u32x4 t; t[0]=u[0]; t[1]=u[1]; t[2]=u[2]; t[3]=u[3];
    dst[mt * 64] = t;
  }
  #pragma unroll
  for (int kt = 0; kt < 2; ++kt)
    #pragma unroll
    for (int mt = 0; mt < 4; ++mt) {
      unsigned u[4];
      #pragma unroll
      for (int wq = 0; wq < 4; ++wq) {
        int k0 = 32*kt + 8*g + 2*wq;
        u[wq] = pk2(W2g[k0*64 + mpsi[mt]], W2g[(k0+1)*64 + mpsi[mt]]);
      }
      u32x4 t; t[0]=u[0]; t[1]=u[1]; t[2]=u[2]; t[3]=u[3];
      dst[(4 + kt*4 + mt) * 64] = t;
    }
  #pragma unroll
  for (int kt = 0; kt < 2; ++kt) {
    unsigned u[4];
    #pragma unroll
    for (int wq = 0; wq < 4; ++wq) {
      int k0 = 32*kt + 8*g + 2*wq;
      float v0 = (q < 12) ? W3g[k0*12 + q]     : 0.f;
      float v1 = (q < 12) ? W3g[(k0+1)*12 + q] : 0.f;
      u[wq] = pk2(v0, v1);
    }
    u32x4 t; t[0]=u[0]; t[1]=u[1]; t[2]=u[2]; t[3]=u[3];
    dst[(12 + kt) * 64] = t;
  }
  #pragma unroll
  for (int mt = 0; mt < 4; ++mt) {
    f32x4 bv;
    #pragma unroll
    for (int r = 0; r < 4; ++r) bv[r] = b2g[32*(mt>>1) + 8*g + 4*(mt&1) + r];
    union { f32x4 f; u32x4 u; } U; U.f = bv;
    dst[(14 + mt) * 64] = U.u;
  }
  {
    f32x4 bv;
    #pragma unroll
    for (int r = 0; r < 4; ++r) {
      int m = 4*g + r;
      bv[r] = (m < 12) ? b3g[m] : 0.f;
    }
    union { f32x4 f; u32x4 u; } U; U.f = bv;
    dst[18 * 64] = U.u;
  }
}

// ================= ROUND-23 = r19 REVERT (best measured: 147.8us bench / 151us prof) =================
// r22 falsified zero-barrier: computing all 4 ports per wave quadrupled weight
// L2 traffic (~1.9GB -> ~7.5GB; FETCH 14->42MB) and cost +48us despite no
// barriers. r19's structure — wave=port, cc-sequential, weights loaded once
// per (s,cc), 3 blocks/CU — is the optimum of the explored space.
// psi-16x16 (r8), unroll-2 (r11), f32 o/y (r17/r18), prepack (r18).
__global__ __launch_bounds__(256, 3) void rrsep(
    const float* __restrict__ y_real, const float* __restrict__ y_imag,
    const u32x4* __restrict__ wsf, float* __restrict__ out)
{
  __shared__ __align__(16) char smem[SMEM_BYTES];
  unsigned short* xs = (unsigned short*)(smem + X_OFF);
  float*          os = (float*)(smem + O_OFF);
  float*          ysf = (float*)(smem + Y_OFF);
  float*          es = (float*)(smem + E_OFF);

  const int tid  = (int)threadIdx.x;
  const int lane = tid & 63;
  const int p    = tid >> 6;     // wave 0..3 = port
  const int q    = lane & 15;
  const int g    = lane >> 4;
  const long r0  = (long)blockIdx.x * RT;

  // ---------------- prologue: coalesced load, normalize, init x ----------------
  {
    float* stg = (float*)smem;   // overlays x region before its first use
    if (tid < 192) {             // 64 rows x 12 = 768 f32 = 192 f32x4 per component
      ((f32x4*)stg)[tid]         = ((const f32x4*)(y_real + r0 * 12))[tid];
      ((f32x4*)(stg + 768))[tid] = ((const f32x4*)(y_imag + r0 * 12))[tid];
    }
    __syncthreads();
    float yv[24]; float ev = 0.f, inv = 0.f;
    if (tid < RT) {
      float acc = 0.f;
      #pragma unroll
      for (int l = 0; l < 12; ++l) {
        yv[l]      = stg[tid * 12 + l];
        yv[12 + l] = stg[768 + tid * 12 + l];
        acc += yv[l] * yv[l] + yv[12 + l] * yv[12 + l];
      }
      ev  = sqrtf(acc * (1.f / 12.f));
      inv = 1.f / (ev + 1e-8f);
    }
    __syncthreads();   // all slab reads done before x/y overwrite the region
    if (tid < RT) {
      es[tid] = ev;
      // y normalized, f32 (r18)
      #pragma unroll
      for (int i = 0; i < 6; ++i) {
        f32x4 t;
        t[0] = yv[4*i+0] * inv; t[1] = yv[4*i+1] * inv;
        t[2] = yv[4*i+2] * inv; t[3] = yv[4*i+3] * inv;
        int l0 = 4*i;
        float* yr = ysf + ((l0 < 12) ? (0 * RT + tid) * 12 + l0 : (1 * RT + tid) * 12 + (l0 - 12));
        *(f32x4*)yr = t;
      }
      unsigned pkw[12];
      #pragma unroll
      for (int j = 0; j < 12; ++j) pkw[j] = pk2(yv[2*j] * inv, yv[2*j+1] * inv);
      #pragma unroll
      for (int p2 = 0; p2 < 4; ++p2) {
        u32x4* xr = (u32x4*)(xs + (p2 * RT + tid) * XSTR);
        u32x4 t0; t0[0]=pkw[0]; t0[1]=pkw[1]; t0[2]=pkw[2]; t0[3]=pkw[3];
        u32x4 t1; t1[0]=pkw[4]; t1[1]=pkw[5]; t1[2]=pkw[6]; t1[3]=pkw[7];
        u32x4 t2; t2[0]=pkw[8]; t2[1]=pkw[9]; t2[2]=pkw[10]; t2[3]=pkw[11];
        u32x4 t3; t3[0]=pk2(1.f, 0.f); t3[1]=0u; t3[2]=0u; t3[3]=0u;  // aug x[24]=1
        xr[0]=t0; xr[1]=t1; xr[2]=t2; xr[3]=t3;
      }
    }
    __syncthreads();
  }

  #pragma unroll 1
  for (int s = 0; s < 3; ++s) {
    // ---------- channel-sequential (r16); weights pre-packed (r18) ----------
    #pragma unroll 1
    for (int cc = 0; cc < 2; ++cc) {
      const int pc = (s * 4 + p) * 2 + cc;
      const u32x4* wb = wsf + pc * NFRAG * 64 + lane;   // frag f at wb[f*64]

      bf16x8 w1f[4], w2f[2][4], w3f[2];
      f32x4 b2f[4], b3f;
      #pragma unroll
      for (int mt = 0; mt < 4; ++mt) {
        union { u32x4 u; bf16x8 v; } U; U.u = wb[mt * 64];
        w1f[mt] = U.v;
      }
      #pragma unroll
      for (int kt = 0; kt < 2; ++kt)
        #pragma unroll
        for (int mt = 0; mt < 4; ++mt) {
          union { u32x4 u; bf16x8 v; } U; U.u = wb[(4 + kt*4 + mt) * 64];
          w2f[kt][mt] = U.v;
        }
      #pragma unroll
      for (int kt = 0; kt < 2; ++kt) {
        union { u32x4 u; bf16x8 v; } U; U.u = wb[(12 + kt) * 64];
        w3f[kt] = U.v;
      }
      #pragma unroll
      for (int mt = 0; mt < 4; ++mt) {
        union { u32x4 u; f32x4 f; } U; U.u = wb[(14 + mt) * 64];
        b2f[mt] = U.f;
      }
      {
        union { u32x4 u; f32x4 f; } U; U.u = wb[18 * 64];
        b3f = U.f;
      }

      // main: 4 chunks of 16 rows; unroll 2 (r11-verified)
      #pragma unroll 2
      for (int ch = 0; ch < RT / 16; ++ch) {
        const int row = ch * 16 + q;
        bf16x8 xb = *(const bf16x8*)(xs + (p * RT + row) * XSTR + 8 * g);

        f32x4 c1[4];
        #pragma unroll
        for (int mt = 0; mt < 4; ++mt) c1[mt] = mfma16(w1f[mt], xb, f32x4{0.f,0.f,0.f,0.f});

        bf16x8 fr1[2];
        #pragma unroll
        for (int kt = 0; kt < 2; ++kt)
          fr1[kt] = mkfrag(
            pk2t(fmaxf(c1[2*kt][0], 0.f),   fmaxf(c1[2*kt][1], 0.f)),
            pk2t(fmaxf(c1[2*kt][2], 0.f),   fmaxf(c1[2*kt][3], 0.f)),
            pk2t(fmaxf(c1[2*kt+1][0], 0.f), fmaxf(c1[2*kt+1][1], 0.f)),
            pk2t(fmaxf(c1[2*kt+1][2], 0.f), fmaxf(c1[2*kt+1][3], 0.f)));

        f32x4 c2[4];
        #pragma unroll
        for (int mt = 0; mt < 4; ++mt) {
          c2[mt] = mfma16(w2f[0][mt], fr1[0], b2f[mt]);
          c2[mt] = mfma16(w2f[1][mt], fr1[1], c2[mt]);
        }
        bf16x8 fr2[2];
        #pragma unroll
        for (int kt = 0; kt < 2; ++kt)
          fr2[kt] = mkfrag(
            pk2t(fmaxf(c2[2*kt][0], 0.f),   fmaxf(c2[2*kt][1], 0.f)),
            pk2t(fmaxf(c2[2*kt][2], 0.f),   fmaxf(c2[2*kt][3], 0.f)),
            pk2t(fmaxf(c2[2*kt+1][0], 0.f), fmaxf(c2[2*kt+1][1], 0.f)),
            pk2t(fmaxf(c2[2*kt+1][2], 0.f), fmaxf(c2[2*kt+1][3], 0.f)));

        f32x4 c3 = mfma16(w3f[0], fr2[0], b3f);
        c3 = mfma16(w3f[1], fr2[1], c3);

        if (g < 3)
          *(f32x4*)(os + ((p * 2 + cc) * 65 + row) * 12 + 4 * g) = c3;
      }
    }
    __syncthreads();

    // ------- residual combine: 256 (r,pp) units = 1/thread (o f32, y f32) -------
    {
      const int r = tid >> 2, pp = tid & 3;
      float sum[24], own[24], yn[24];
      #pragma unroll
      for (int k = 0; k < 24; ++k) sum[k] = 0.f;
      #pragma unroll
      for (int pp2 = 0; pp2 < 4; ++pp2)
        #pragma unroll
        for (int cc2 = 0; cc2 < 2; ++cc2) {
          const f32x4* orow = (const f32x4*)(os + ((pp2 * 2 + cc2) * 65 + r) * 12);
          #pragma unroll
          for (int i = 0; i < 3; ++i) {
            f32x4 t = orow[i];
            sum[cc2*12 + 4*i + 0] += t[0];
            sum[cc2*12 + 4*i + 1] += t[1];
            sum[cc2*12 + 4*i + 2] += t[2];
            sum[cc2*12 + 4*i + 3] += t[3];
          }
        }
      #pragma unroll
      for (int cc2 = 0; cc2 < 2; ++cc2) {
        const f32x4* orow = (const f32x4*)(os + ((pp * 2 + cc2) * 65 + r) * 12);
        const f32x4* yrow = (const f32x4*)(ysf + (cc2 * RT + r) * 12);
        #pragma unroll
        for (int i = 0; i < 3; ++i) {
          f32x4 t = orow[i], u = yrow[i];
          own[cc2*12 + 4*i + 0] = t[0]; yn[cc2*12 + 4*i + 0] = u[0];
          own[cc2*12 + 4*i + 1] = t[1]; yn[cc2*12 + 4*i + 1] = u[1];
          own[cc2*12 + 4*i + 2] = t[2]; yn[cc2*12 + 4*i + 2] = u[2];
          own[cc2*12 + 4*i + 3] = t[3]; yn[cc2*12 + 4*i + 3] = u[3];
        }
      }
      if (s < 2) {
        unsigned xw[12];
        #pragma unroll
        for (int j = 0; j < 12; ++j) {
          float v0 = own[2*j]   + (yn[2*j]   - sum[2*j]);
          float v1 = own[2*j+1] + (yn[2*j+1] - sum[2*j+1]);
          xw[j] = pk2(v0, v1);
        }
        u32x4* xr = (u32x4*)(xs + (pp * RT + r) * XSTR);
        u32x4 t0; t0[0]=xw[0]; t0[1]=xw[1]; t0[2]=xw[2];  t0[3]=xw[3];
        u32x4 t1; t1[0]=xw[4]; t1[1]=xw[5]; t1[2]=xw[6];  t1[3]=xw[7];
        u32x4 t2; t2[0]=xw[8]; t2[1]=xw[9]; t2[2]=xw[10]; t2[3]=xw[11];
        xr[0]=t0; xr[1]=t1; xr[2]=t2;
        __syncthreads();
      } else {
        const float ev = es[r];
        float vals[24];
        #pragma unroll
        for (int l = 0; l < 12; ++l) {
          vals[2*l]   = (own[l]      + yn[l]      - sum[l])      * ev;
          vals[2*l+1] = (own[12 + l] + yn[12 + l] - sum[12 + l]) * ev;
        }
        __syncthreads();                       // all o/y/e reads done
        float* vstg = (float*)smem;            // overlays x + front of o (24,576 B)
        f32x4* vw = (f32x4*)(vstg + r * 96 + pp * 24);
        #pragma unroll
        for (int i = 0; i < 6; ++i) {
          f32x4 t; t[0]=vals[4*i]; t[1]=vals[4*i+1]; t[2]=vals[4*i+2]; t[3]=vals[4*i+3];
          vw[i] = t;
        }
        __syncthreads();
        const f32x4* vp = (const f32x4*)vstg;
        f32x4* og = (f32x4*)(out + r0 * 96);
        #pragma unroll
        for (int i = 0; i < 6; ++i) og[tid + 256 * i] = vp[tid + 256 * i];
      }
    }
  }
}

extern "C" void kernel_launch(void* const* d_in, const int* in_sizes, int n_in,
                              void* d_out, int out_size, void* d_ws, size_t ws_size,
                              hipStream_t stream) {
  const float* y_real = (const float*)d_in[0];
  const float* y_imag = (const float*)d_in[1];
  const float* W1 = (const float*)d_in[2];
  const float* b1 = (const float*)d_in[3];
  const float* W2 = (const float*)d_in[4];
  const float* b2 = (const float*)d_in[5];
  const float* W3 = (const float*)d_in[6];
  const float* b3 = (const float*)d_in[7];
  float* out = (float*)d_out;
  u32x4* ws = (u32x4*)d_ws;   // needs 24*19*64*16 = 466,944 B

  hipLaunchKernelGGL(wpack, dim3(24), dim3(64), 0, stream,
                     W1, b1, W2, b2, W3, b3, ws);
  hipLaunchKernelGGL(rrsep, dim3(NB), dim3(256), 0, stream,
                     y_real, y_imag, ws, out);
}

// Round 24
// 143.764 us; speedup vs baseline: 1.2858x; 1.0425x over previous
//
#include <hip/hip_runtime.h>
#include <hip/hip_bf16.h>

typedef __attribute__((ext_vector_type(8))) short bf16x8;
typedef __attribute__((ext_vector_type(4))) float f32x4;
typedef __attribute__((ext_vector_type(4))) unsigned int u32x4;
typedef unsigned long long ull;

#define RT 64
#define NB (262144 / RT)
#define XSTR 32
#define NFRAG 19   // 0-3 w1f, 4-11 w2f[kt*4+mt], 12-13 w3f, 14-17 b2f, 18 b3f

// LDS byte offsets — 47,744 B/block -> 3 blocks/CU (143.2KB <= 160KB)
#define X_OFF 0          // x: [4][64][32] bf16    = 16384 B
#define O_OFF 16384      // o: [4][2][65][12] f32  = 24960 B
#define Y_OFF 41344      // y: [2][64][12] f32     =  6144 B
#define E_OFF 47488      // e: [64] f32            =   256 B
#define SMEM_BYTES 47744

// RNE 3-VALU pack (r6-verified) — weights / state / prologue.
__device__ __forceinline__ unsigned pk2(float lo, float hi) {
  union { float f; unsigned u; } a, b;
  a.f = lo; b.f = hi;
  return __builtin_amdgcn_perm(b.u + 0x8000u, a.u + 0x8000u, 0x07060302u);
}
// truncating 1-VALU pack for inter-layer activations (r17-verified)
__device__ __forceinline__ unsigned pk2t(float lo, float hi) {
  union { float f; unsigned u; } a, b;
  a.f = lo; b.f = hi;
  return __builtin_amdgcn_perm(b.u, a.u, 0x07060302u);
}
// ROUND-24 SINGLE DELTA: DPP quad-sum. Threads 4r+pp (pp=0..3) form a quad
// holding the 4 ports of row r; two quad_perm butterflies (xor1=0xB1 [1,0,3,2],
// xor2=0x4E [2,3,0,1]) give the port-sum in-register. Replaces the all-ports
// LDS loop (24 reads + 96 adds/thread/stage). DPP tested ISOLATED here —
// r4's NaN was proven (r5 A/B) to be the asm cvt_pk, not DPP.
__device__ __forceinline__ float qsum4(float v) {
  union { float f; int i; } a, b;
  a.f = v;
  b.i = __builtin_amdgcn_update_dpp(0, a.i, 0xB1, 0xF, 0xF, true);
  float s1 = v + b.f;
  a.f = s1;
  b.i = __builtin_amdgcn_update_dpp(0, a.i, 0x4E, 0xF, 0xF, true);
  return s1 + b.f;
}
__device__ __forceinline__ bf16x8 mkfrag(unsigned w0, unsigned w1, unsigned w2, unsigned w3) {
  union { bf16x8 v; unsigned u[4]; } U;
  U.u[0] = w0; U.u[1] = w1; U.u[2] = w2; U.u[3] = w3;
  return U.v;
}
__device__ __forceinline__ f32x4 mfma16(bf16x8 a, bf16x8 b, f32x4 c) {
  return __builtin_amdgcn_mfma_f32_16x16x32_bf16(a, b, c, 0, 0, 0);
}

// ================= prep kernel: pack weight fragments once (r18-verified) =================
__global__ void wpack(const float* __restrict__ W1, const float* __restrict__ b1,
                      const float* __restrict__ W2, const float* __restrict__ b2,
                      const float* __restrict__ W3, const float* __restrict__ b3,
                      u32x4* __restrict__ ws)
{
  const int pc = blockIdx.x;       // 0..23 = (s*4+p)*2+c
  const int lane = threadIdx.x;    // 0..63
  const int q = lane & 15, g = lane >> 4;
  int mpsi[4];
  #pragma unroll
  for (int mt = 0; mt < 4; ++mt)
    mpsi[mt] = 32*(mt>>1) + 8*(q>>2) + 4*(mt&1) + (q&3);

  const float* W1g = W1 + pc * 24 * 64;
  const float* b1g = b1 + pc * 64;
  const float* W2g = W2 + pc * 64 * 64;
  const float* b2g = b2 + pc * 64;
  const float* W3g = W3 + pc * 64 * 12;
  const float* b3g = b3 + pc * 12;
  u32x4* dst = ws + pc * NFRAG * 64 + lane;   // frag f at dst[f*64]

  #pragma unroll
  for (int mt = 0; mt < 4; ++mt) {
    unsigned u[4];
    #pragma unroll
    for (int wq = 0; wq < 4; ++wq) {
      int k0 = 8*g + 2*wq;
      float v0 = (k0 < 24) ? W1g[k0*64 + mpsi[mt]] : ((k0 == 24) ? b1g[mpsi[mt]] : 0.f);
      float v1 = (k0+1 < 24) ? W1g[(k0+1)*64 + mpsi[mt]] : 0.f;
      u[wq] = pk2(v0, v1);
    }
    u32x4 t; t[0]=u[0]; t[1]=u[1]; t[2]=u[2]; t[3]=u[3];
    dst[mt * 64] = t;
  }
  #pragma unroll
  for (int kt = 0; kt < 2; ++kt)
    #pragma unroll
    for (int mt = 0; mt < 4; ++mt) {
      unsigned u[4];
      #pragma unroll
      for (int wq = 0; wq < 4; ++wq) {
        int k0 = 32*kt + 8*g + 2*wq;
        u[wq] = pk2(W2g[k0*64 + mpsi[mt]], W2g[(k0+1)*64 + mpsi[mt]]);
      }
      u32x4 t; t[0]=u[0]; t[1]=u[1]; t[2]=u[2]; t[3]=u[3];
      dst[(4 + kt*4 + mt) * 64] = t;
    }
  #pragma unroll
  for (int kt = 0; kt < 2; ++kt) {
    unsigned u[4];
    #pragma unroll
    for (int wq = 0; wq < 4; ++wq) {
      int k0 = 32*kt + 8*g + 2*wq;
      float v0 = (q < 12) ? W3g[k0*12 + q]     : 0.f;
      float v1 = (q < 12) ? W3g[(k0+1)*12 + q] : 0.f;
      u[wq] = pk2(v0, v1);
    }
    u32x4 t; t[0]=u[0]; t[1]=u[1]; t[2]=u[2]; t[3]=u[3];
    dst[(12 + kt) * 64] = t;
  }
  #pragma unroll
  for (int mt = 0; mt < 4; ++mt) {
    f32x4 bv;
    #pragma unroll
    for (int r = 0; r < 4; ++r) bv[r] = b2g[32*(mt>>1) + 8*g + 4*(mt&1) + r];
    union { f32x4 f; u32x4 u; } U; U.f = bv;
    dst[(14 + mt) * 64] = U.u;
  }
  {
    f32x4 bv;
    #pragma unroll
    for (int r = 0; r < 4; ++r) {
      int m = 4*g + r;
      bv[r] = (m < 12) ? b3g[m] : 0.f;
    }
    union { f32x4 f; u32x4 u; } U; U.f = bv;
    dst[18 * 64] = U.u;
  }
}

// ================= ROUND-24 main = r19/r23 base + DPP quad-sum combine =================
// r23 reproduced the optimum (149.9/151us). Single delta: the combine's
// port-sum via qsum4 (thread reads only its OWN port's o-rows; 18 LDS reads
// + ~48 VALU saved per thread per stage).
__global__ __launch_bounds__(256, 3) void rrsep(
    const float* __restrict__ y_real, const float* __restrict__ y_imag,
    const u32x4* __restrict__ wsf, float* __restrict__ out)
{
  __shared__ __align__(16) char smem[SMEM_BYTES];
  unsigned short* xs = (unsigned short*)(smem + X_OFF);
  float*          os = (float*)(smem + O_OFF);
  float*          ysf = (float*)(smem + Y_OFF);
  float*          es = (float*)(smem + E_OFF);

  const int tid  = (int)threadIdx.x;
  const int lane = tid & 63;
  const int p    = tid >> 6;     // wave 0..3 = port
  const int q    = lane & 15;
  const int g    = lane >> 4;
  const long r0  = (long)blockIdx.x * RT;

  // ---------------- prologue: coalesced load, normalize, init x ----------------
  {
    float* stg = (float*)smem;   // overlays x region before its first use
    if (tid < 192) {             // 64 rows x 12 = 768 f32 = 192 f32x4 per component
      ((f32x4*)stg)[tid]         = ((const f32x4*)(y_real + r0 * 12))[tid];
      ((f32x4*)(stg + 768))[tid] = ((const f32x4*)(y_imag + r0 * 12))[tid];
    }
    __syncthreads();
    float yv[24]; float ev = 0.f, inv = 0.f;
    if (tid < RT) {
      float acc = 0.f;
      #pragma unroll
      for (int l = 0; l < 12; ++l) {
        yv[l]      = stg[tid * 12 + l];
        yv[12 + l] = stg[768 + tid * 12 + l];
        acc += yv[l] * yv[l] + yv[12 + l] * yv[12 + l];
      }
      ev  = sqrtf(acc * (1.f / 12.f));
      inv = 1.f / (ev + 1e-8f);
    }
    __syncthreads();   // all slab reads done before x/y overwrite the region
    if (tid < RT) {
      es[tid] = ev;
      // y normalized, f32 (r18)
      #pragma unroll
      for (int i = 0; i < 6; ++i) {
        f32x4 t;
        t[0] = yv[4*i+0] * inv; t[1] = yv[4*i+1] * inv;
        t[2] = yv[4*i+2] * inv; t[3] = yv[4*i+3] * inv;
        int l0 = 4*i;
        float* yr = ysf + ((l0 < 12) ? (0 * RT + tid) * 12 + l0 : (1 * RT + tid) * 12 + (l0 - 12));
        *(f32x4*)yr = t;
      }
      unsigned pkw[12];
      #pragma unroll
      for (int j = 0; j < 12; ++j) pkw[j] = pk2(yv[2*j] * inv, yv[2*j+1] * inv);
      #pragma unroll
      for (int p2 = 0; p2 < 4; ++p2) {
        u32x4* xr = (u32x4*)(xs + (p2 * RT + tid) * XSTR);
        u32x4 t0; t0[0]=pkw[0]; t0[1]=pkw[1]; t0[2]=pkw[2]; t0[3]=pkw[3];
        u32x4 t1; t1[0]=pkw[4]; t1[1]=pkw[5]; t1[2]=pkw[6]; t1[3]=pkw[7];
        u32x4 t2; t2[0]=pkw[8]; t2[1]=pkw[9]; t2[2]=pkw[10]; t2[3]=pkw[11];
        u32x4 t3; t3[0]=pk2(1.f, 0.f); t3[1]=0u; t3[2]=0u; t3[3]=0u;  // aug x[24]=1
        xr[0]=t0; xr[1]=t1; xr[2]=t2; xr[3]=t3;
      }
    }
    __syncthreads();
  }

  #pragma unroll 1
  for (int s = 0; s < 3; ++s) {
    // ---------- channel-sequential (r16); weights pre-packed (r18) ----------
    #pragma unroll 1
    for (int cc = 0; cc < 2; ++cc) {
      const int pc = (s * 4 + p) * 2 + cc;
      const u32x4* wb = wsf + pc * NFRAG * 64 + lane;   // frag f at wb[f*64]

      bf16x8 w1f[4], w2f[2][4], w3f[2];
      f32x4 b2f[4], b3f;
      #pragma unroll
      for (int mt = 0; mt < 4; ++mt) {
        union { u32x4 u; bf16x8 v; } U; U.u = wb[mt * 64];
        w1f[mt] = U.v;
      }
      #pragma unroll
      for (int kt = 0; kt < 2; ++kt)
        #pragma unroll
        for (int mt = 0; mt < 4; ++mt) {
          union { u32x4 u; bf16x8 v; } U; U.u = wb[(4 + kt*4 + mt) * 64];
          w2f[kt][mt] = U.v;
        }
      #pragma unroll
      for (int kt = 0; kt < 2; ++kt) {
        union { u32x4 u; bf16x8 v; } U; U.u = wb[(12 + kt) * 64];
        w3f[kt] = U.v;
      }
      #pragma unroll
      for (int mt = 0; mt < 4; ++mt) {
        union { u32x4 u; f32x4 f; } U; U.u = wb[(14 + mt) * 64];
        b2f[mt] = U.f;
      }
      {
        union { u32x4 u; f32x4 f; } U; U.u = wb[18 * 64];
        b3f = U.f;
      }

      // main: 4 chunks of 16 rows; unroll 2 (r11-verified)
      #pragma unroll 2
      for (int ch = 0; ch < RT / 16; ++ch) {
        const int row = ch * 16 + q;
        bf16x8 xb = *(const bf16x8*)(xs + (p * RT + row) * XSTR + 8 * g);

        f32x4 c1[4];
        #pragma unroll
        for (int mt = 0; mt < 4; ++mt) c1[mt] = mfma16(w1f[mt], xb, f32x4{0.f,0.f,0.f,0.f});

        bf16x8 fr1[2];
        #pragma unroll
        for (int kt = 0; kt < 2; ++kt)
          fr1[kt] = mkfrag(
            pk2t(fmaxf(c1[2*kt][0], 0.f),   fmaxf(c1[2*kt][1], 0.f)),
            pk2t(fmaxf(c1[2*kt][2], 0.f),   fmaxf(c1[2*kt][3], 0.f)),
            pk2t(fmaxf(c1[2*kt+1][0], 0.f), fmaxf(c1[2*kt+1][1], 0.f)),
            pk2t(fmaxf(c1[2*kt+1][2], 0.f), fmaxf(c1[2*kt+1][3], 0.f)));

        f32x4 c2[4];
        #pragma unroll
        for (int mt = 0; mt < 4; ++mt) {
          c2[mt] = mfma16(w2f[0][mt], fr1[0], b2f[mt]);
          c2[mt] = mfma16(w2f[1][mt], fr1[1], c2[mt]);
        }
        bf16x8 fr2[2];
        #pragma unroll
        for (int kt = 0; kt < 2; ++kt)
          fr2[kt] = mkfrag(
            pk2t(fmaxf(c2[2*kt][0], 0.f),   fmaxf(c2[2*kt][1], 0.f)),
            pk2t(fmaxf(c2[2*kt][2], 0.f),   fmaxf(c2[2*kt][3], 0.f)),
            pk2t(fmaxf(c2[2*kt+1][0], 0.f), fmaxf(c2[2*kt+1][1], 0.f)),
            pk2t(fmaxf(c2[2*kt+1][2], 0.f), fmaxf(c2[2*kt+1][3], 0.f)));

        f32x4 c3 = mfma16(w3f[0], fr2[0], b3f);
        c3 = mfma16(w3f[1], fr2[1], c3);

        if (g < 3)
          *(f32x4*)(os + ((p * 2 + cc) * 65 + row) * 12 + 4 * g) = c3;
      }
    }
    __syncthreads();

    // ------- residual combine: thread (r,pp) reads OWN port only; port-sum via DPP -------
    {
      const int r = tid >> 2, pp = tid & 3;
      float own[24], yn[24], sum[24];
      #pragma unroll
      for (int cc2 = 0; cc2 < 2; ++cc2) {
        const f32x4* orow = (const f32x4*)(os + ((pp * 2 + cc2) * 65 + r) * 12);
        const f32x4* yrow = (const f32x4*)(ysf + (cc2 * RT + r) * 12);
        #pragma unroll
        for (int i = 0; i < 3; ++i) {
          f32x4 t = orow[i], u = yrow[i];
          own[cc2*12 + 4*i + 0] = t[0]; yn[cc2*12 + 4*i + 0] = u[0];
          own[cc2*12 + 4*i + 1] = t[1]; yn[cc2*12 + 4*i + 1] = u[1];
          own[cc2*12 + 4*i + 2] = t[2]; yn[cc2*12 + 4*i + 2] = u[2];
          own[cc2*12 + 4*i + 3] = t[3]; yn[cc2*12 + 4*i + 3] = u[3];
        }
      }
      #pragma unroll
      for (int k = 0; k < 24; ++k) sum[k] = qsum4(own[k]);   // ports 0..3 of row r

      if (s < 2) {
        unsigned xw[12];
        #pragma unroll
        for (int j = 0; j < 12; ++j) {
          float v0 = own[2*j]   + (yn[2*j]   - sum[2*j]);
          float v1 = own[2*j+1] + (yn[2*j+1] - sum[2*j+1]);
          xw[j] = pk2(v0, v1);
        }
        u32x4* xr = (u32x4*)(xs + (pp * RT + r) * XSTR);
        u32x4 t0; t0[0]=xw[0]; t0[1]=xw[1]; t0[2]=xw[2];  t0[3]=xw[3];
        u32x4 t1; t1[0]=xw[4]; t1[1]=xw[5]; t1[2]=xw[6];  t1[3]=xw[7];
        u32x4 t2; t2[0]=xw[8]; t2[1]=xw[9]; t2[2]=xw[10]; t2[3]=xw[11];
        xr[0]=t0; xr[1]=t1; xr[2]=t2;
        __syncthreads();
      } else {
        const float ev = es[r];
        float vals[24];
        #pragma unroll
        for (int l = 0; l < 12; ++l) {
          vals[2*l]   = (own[l]      + yn[l]      - sum[l])      * ev;
          vals[2*l+1] = (own[12 + l] + yn[12 + l] - sum[12 + l]) * ev;
        }
        __syncthreads();                       // all o/y/e reads done
        float* vstg = (float*)smem;            // overlays x + front of o (24,576 B)
        f32x4* vw = (f32x4*)(vstg + r * 96 + pp * 24);
        #pragma unroll
        for (int i = 0; i < 6; ++i) {
          f32x4 t; t[0]=vals[4*i]; t[1]=vals[4*i+1]; t[2]=vals[4*i+2]; t[3]=vals[4*i+3];
          vw[i] = t;
        }
        __syncthreads();
        const f32x4* vp = (const f32x4*)vstg;
        f32x4* og = (f32x4*)(out + r0 * 96);
        #pragma unroll
        for (int i = 0; i < 6; ++i) og[tid + 256 * i] = vp[tid + 256 * i];
      }
    }
  }
}

extern "C" void kernel_launch(void* const* d_in, const int* in_sizes, int n_in,
                              void* d_out, int out_size, void* d_ws, size_t ws_size,
                              hipStream_t stream) {
  const float* y_real = (const float*)d_in[0];
  const float* y_imag = (const float*)d_in[1];
  const float* W1 = (const float*)d_in[2];
  const float* b1 = (const float*)d_in[3];
  const float* W2 = (const float*)d_in[4];
  const float* b2 = (const float*)d_in[5];
  const float* W3 = (const float*)d_in[6];
  const float* b3 = (const float*)d_in[7];
  float* out = (float*)d_out;
  u32x4* ws = (u32x4*)d_ws;   // needs 24*19*64*16 = 466,944 B

  hipLaunchKernelGGL(wpack, dim3(24), dim3(64), 0, stream,
                     W1, b1, W2, b2, W3, b3, ws);
  hipLaunchKernelGGL(rrsep, dim3(NB), dim3(256), 0, stream,
                     y_real, y_imag, ws, out);
}